// Round 9
// baseline (381.843 us; speedup 1.0000x reference)
//
#include <hip/hip_runtime.h>
#include <math.h>

#define SB 4
#define SS 2048
#define SD 1024
#define SH 16
#define KTOP 409   // max(2048//5, 1)
#define KSL 8      // xbar split-K slices
#define KPS 52     // ceil(KTOP/KSL)

typedef float f32x4  __attribute__((ext_vector_type(4)));
typedef short bf16x8 __attribute__((ext_vector_type(8)));
typedef short s16x4  __attribute__((ext_vector_type(4)));

__device__ __forceinline__ short f2bf(float x) {
  unsigned u = __float_as_uint(x);
  u += 0x7fff + ((u >> 16) & 1);           // RNE
  return (short)(u >> 16);
}
__device__ __forceinline__ float bf2f(short s) {
  return __uint_as_float(((unsigned)(unsigned short)s) << 16);
}

// async global->LDS, 16B per lane; LDS base must be wave-uniform (HW adds lane*16B)
__device__ __forceinline__ void gld16(const void* g, void* l) {
  __builtin_amdgcn_global_load_lds(
      (const __attribute__((address_space(1))) void*)g,
      (__attribute__((address_space(3))) void*)l, 16, 0, 0);
}

// XOR bank-swizzle for FFT LDS arrays (float2 granularity: bank-pair = idx mod 16).
// Folds BOTH upper nibbles into the bank bits. NOTE: XS(i+1024) != XS(i)+1024
// for this swizzle — always compute XS() explicitly per index.
#define XS(i) ((i) ^ ((((i) >> 4) ^ ((i) >> 8)) & 15))

// ---- 2048-pt FFT cores: radix-2 stage + 5 fused radix-4 DIT stages ------------
template<int SIGN>
__device__ __forceinline__ void fft2048_lds(float2* z, const float2* tw, int tid) {
#pragma unroll
  for (int l = 0; l < 4; ++l) {
    int bf = tid + l * 256;                 // 0..1023
    int i0 = XS(2 * bf), i1 = XS(2 * bf + 1);
    float2 a = z[i0], b = z[i1];
    z[i0] = make_float2(a.x + b.x, a.y + b.y);
    z[i1] = make_float2(a.x - b.x, a.y - b.y);
  }
  __syncthreads();
#pragma unroll
  for (int lq = 1; lq <= 9; lq += 2) {
    const int q = 1 << lq;
#pragma unroll
    for (int l = 0; l < 2; ++l) {
      int bf = tid + l * 256;               // 0..511
      int p = bf & (q - 1);
      int base = ((bf >> lq) << (lq + 2)) + p;
      int e1 = p << (9 - lq);
      int e2 = e1 << 1;
      int e3 = e1 * 3;
      float2 w1 = tw[XS(e1)];
      float2 w2 = tw[XS(e2)];
      float s3 = 1.f; int e3w = e3;
      if (e3 >= 1024) { e3w = e3 - 1024; s3 = -1.f; }
      float2 w3 = tw[XS(e3w)]; w3.x *= s3; w3.y *= s3;
      float2 t0 = z[XS(base)];
      float2 vb = z[XS(base + 2 * q)];      // j=1
      float2 vc = z[XS(base + q)];          // j=2
      float2 vd = z[XS(base + 3 * q)];      // j=3
      float w1i = SIGN * w1.y, w2i = SIGN * w2.y, w3i = SIGN * w3.y;
      float2 t1 = make_float2(vb.x * w1.x - vb.y * w1i, vb.x * w1i + vb.y * w1.x);
      float2 t2 = make_float2(vc.x * w2.x - vc.y * w2i, vc.x * w2i + vc.y * w2.x);
      float2 t3 = make_float2(vd.x * w3.x - vd.y * w3i, vd.x * w3i + vd.y * w3.x);
      float2 s02 = make_float2(t0.x + t2.x, t0.y + t2.y);
      float2 d02 = make_float2(t0.x - t2.x, t0.y - t2.y);
      float2 s13 = make_float2(t1.x + t3.x, t1.y + t3.y);
      float2 d13 = make_float2(t1.x - t3.x, t1.y - t3.y);
      float2 r13 = make_float2(SIGN * d13.y, -SIGN * d13.x);
      z[XS(base)]         = make_float2(s02.x + s13.x, s02.y + s13.y);
      z[XS(base + q)]     = make_float2(d02.x + r13.x, d02.y + r13.y);
      z[XS(base + 2 * q)] = make_float2(s02.x - s13.x, s02.y - s13.y);
      z[XS(base + 3 * q)] = make_float2(d02.x - r13.x, d02.y - r13.y);
    }
    __syncthreads();
  }
}

// Dual-buffer variant: two independent FFTs advance in lockstep under ONE sync
// ladder; twiddle index math + loads shared between the two butterflies.
template<int SIGN>
__device__ __forceinline__ void fft2048x2_lds(
    float2* __restrict__ z0, float2* __restrict__ z1,
    const float2* tw, int tid)
{
#pragma unroll
  for (int l = 0; l < 4; ++l) {
    int bf = tid + l * 256;                 // 0..1023
    int i0 = XS(2 * bf), i1 = XS(2 * bf + 1);
    float2 a0 = z0[i0], b0 = z0[i1];
    float2 a1 = z1[i0], b1 = z1[i1];
    z0[i0] = make_float2(a0.x + b0.x, a0.y + b0.y);
    z0[i1] = make_float2(a0.x - b0.x, a0.y - b0.y);
    z1[i0] = make_float2(a1.x + b1.x, a1.y + b1.y);
    z1[i1] = make_float2(a1.x - b1.x, a1.y - b1.y);
  }
  __syncthreads();
#pragma unroll
  for (int lq = 1; lq <= 9; lq += 2) {
    const int q = 1 << lq;
#pragma unroll
    for (int l = 0; l < 2; ++l) {
      int bf = tid + l * 256;               // 0..511
      int p = bf & (q - 1);
      int base = ((bf >> lq) << (lq + 2)) + p;
      int e1 = p << (9 - lq);
      int e2 = e1 << 1;
      int e3 = e1 * 3;
      float2 w1 = tw[XS(e1)];
      float2 w2 = tw[XS(e2)];
      float s3 = 1.f; int e3w = e3;
      if (e3 >= 1024) { e3w = e3 - 1024; s3 = -1.f; }
      float2 w3 = tw[XS(e3w)]; w3.x *= s3; w3.y *= s3;
      float w1i = SIGN * w1.y, w2i = SIGN * w2.y, w3i = SIGN * w3.y;
      const int ia = XS(base), ib = XS(base + 2 * q),
                ic = XS(base + q), id = XS(base + 3 * q);
#pragma unroll
      for (int s = 0; s < 2; ++s) {
        float2* z = s ? z1 : z0;
        float2 t0 = z[ia];
        float2 vb = z[ib];                  // j=1
        float2 vc = z[ic];                  // j=2
        float2 vd = z[id];                  // j=3
        float2 t1 = make_float2(vb.x * w1.x - vb.y * w1i, vb.x * w1i + vb.y * w1.x);
        float2 t2 = make_float2(vc.x * w2.x - vc.y * w2i, vc.x * w2i + vc.y * w2.x);
        float2 t3 = make_float2(vd.x * w3.x - vd.y * w3i, vd.x * w3i + vd.y * w3.x);
        float2 s02 = make_float2(t0.x + t2.x, t0.y + t2.y);
        float2 d02 = make_float2(t0.x - t2.x, t0.y - t2.y);
        float2 s13 = make_float2(t1.x + t3.x, t1.y + t3.y);
        float2 d13 = make_float2(t1.x - t3.x, t1.y - t3.y);
        float2 r13 = make_float2(SIGN * d13.y, -SIGN * d13.x);
        z[ia] = make_float2(s02.x + s13.x, s02.y + s13.y);
        z[ic] = make_float2(d02.x + r13.x, d02.y + r13.y);
        z[ib] = make_float2(s02.x - s13.x, s02.y - s13.y);
        z[id] = make_float2(d02.x - r13.x, d02.y - r13.y);
      }
    }
    __syncthreads();
  }
}

// in-block twiddle table build: tw[XS(j)] = exp(-2pi i j/2048), hidden under loads
__device__ __forceinline__ void build_tw(float2* tw, int tid) {
  for (int j = tid; j < 1024; j += 256) {
    float a = 6.2831853071795864769f * (float)j / 2048.0f;
    tw[XS(j)] = make_float2(cosf(a), -sinf(a));
  }
}

// ---------------- P0: transpose + split W[k][n] -> Wt[n][{hi:0..1023|lo:1024..2047}]
// BK=32 pre-swizzle: 8-elem group g within each 32-elem span XORed with (n>>1)&3.
__global__ __launch_bounds__(256) void splitwt_k(
    const float* __restrict__ wq, const float* __restrict__ wk,
    short* __restrict__ wqt, short* __restrict__ wkt)
{
  const float* W = blockIdx.z ? wk : wq;
  short* Wt = blockIdx.z ? wkt : wqt;
  const int n0 = blockIdx.x * 64, k0 = blockIdx.y * 64;
  __shared__ float T[64][65];
  const int tid = threadIdx.x;
#pragma unroll
  for (int l = 0; l < 4; ++l) {
    int idx = tid + l * 256;
    int r = idx >> 4, c4 = (idx & 15) << 2;
    float4 v = *(const float4*)&W[(size_t)(k0 + r) * SD + n0 + c4];
    T[r][c4 + 0] = v.x; T[r][c4 + 1] = v.y; T[r][c4 + 2] = v.z; T[r][c4 + 3] = v.w;
  }
  __syncthreads();
#pragma unroll
  for (int l = 0; l < 4; ++l) {
    int idx = tid + l * 256;
    int nr = idx >> 4, k4 = (idx & 15) << 2;
    s16x4 hi, lo;
#pragma unroll
    for (int j = 0; j < 4; ++j) {
      float x = T[k4 + j][nr];
      short hb = f2bf(x);
      hi[j] = hb; lo[j] = f2bf(x - bf2f(hb));
    }
    int ks = (k4 & 32) | (((((k4 >> 3) & 3) ^ ((nr >> 1) & 3))) << 3) | (k4 & 7);
    *(s16x4*)&Wt[(size_t)(n0 + nr) * 2048 + k0 + ks] = hi;
    *(s16x4*)&Wt[(size_t)(n0 + nr) * 2048 + 1024 + k0 + ks] = lo;
  }
}

// ---------------- P0b: split X rows -> Xh/Xl bf16, pre-swizzled (BK=32 map) ----
__global__ __launch_bounds__(256) void splitx2_k(
    const float* __restrict__ Xq, const float* __restrict__ Xk,
    short* __restrict__ Xqh, short* __restrict__ Xql,
    short* __restrict__ Xkh, short* __restrict__ Xkl)
{
  const int tid = threadIdx.x;
  const int row = blockIdx.x * 2 + (tid >> 7);
  const int G = tid & 127;                  // 8-elem group within the row
  const float* X = blockIdx.y ? Xk : Xq;
  short* Xh = blockIdx.y ? Xkh : Xqh;
  short* Xl = blockIdx.y ? Xkl : Xql;
  const float* src = X + ((size_t)row << 10) + (G << 3);
  float4 a = *(const float4*)src;
  float4 b = *(const float4*)(src + 4);
  float xs[8] = {a.x, a.y, a.z, a.w, b.x, b.y, b.z, b.w};
  bf16x8 hi, lo;
#pragma unroll
  for (int j = 0; j < 8; ++j) {
    short hb = f2bf(xs[j]);
    hi[j] = hb; lo[j] = f2bf(xs[j] - bf2f(hb));
  }
  int Gd = (G & ~3) | ((G ^ (row >> 1)) & 3);   // swizzle group within 32-span
  size_t d = ((size_t)row << 10) + (Gd << 3);
  *(bf16x8*)&Xh[d] = hi;
  *(bf16x8*)&Xl[d] = lo;
}

// ---------------- K1: split-bf16 MFMA projection, 128x128 tile, BK=32 ----------
// 32KB LDS -> 4 blocks/CU co-resident (vs 2 at BK=64): barrier-drain stalls
// hide behind other blocks' MFMA. grid (nb, mb, nz) with XCD-locality remap.
__global__ __launch_bounds__(256) void projm_k(
    const short* __restrict__ Xqh, const short* __restrict__ Xql,
    const short* __restrict__ Wq_, const float* __restrict__ bq_,
    float* __restrict__ Oq_,
    const short* __restrict__ Xkh, const short* __restrict__ Xkl,
    const short* __restrict__ Wk_, const float* __restrict__ bk_,
    float* __restrict__ Ok_, int ldT)
{
  const int total = gridDim.x * gridDim.y * gridDim.z;
  int g = blockIdx.x + gridDim.x * (blockIdx.y + gridDim.y * blockIdx.z);
  int t = ((total & 7) == 0) ? (((g & 7) * (total >> 3)) + (g >> 3)) : g;
  const int nb = t % gridDim.x;
  int tmp = t / gridDim.x;
  const int mb = tmp % gridDim.y;
  const int zb = tmp / gridDim.y;

  const short* Xh; const short* Xl; const short* Wt; const float* bias; float* Out;
  if (zb == 0) { Xh = Xqh; Xl = Xql; Wt = Wq_; bias = bq_; Out = Oq_; }
  else         { Xh = Xkh; Xl = Xkl; Wt = Wk_; bias = bk_; Out = Ok_; }
  const int n0 = nb * 128, m0 = mb * 128;
  __shared__ __align__(16) short Ah[128 * 32];
  __shared__ __align__(16) short Al[128 * 32];
  __shared__ __align__(16) short Bh[128 * 32];
  __shared__ __align__(16) short Bl[128 * 32];
  const int tid = threadIdx.x;
  const int wave = tid >> 6, lane = tid & 63, l15 = lane & 15, kq = lane >> 4;
  const int wr = wave >> 1, wc = wave & 1;
  f32x4 acc[4][4];
#pragma unroll
  for (int i = 0; i < 4; ++i)
#pragma unroll
    for (int j = 0; j < 4; ++j)
#pragma unroll
      for (int r = 0; r < 4; ++r) acc[i][j][r] = 0.f;
  float bval[4];
#pragma unroll
  for (int j = 0; j < 4; ++j) bval[j] = bias[n0 + wc * 64 + j * 16 + l15];

  for (int s = 0; s < 32; ++s) {
    __syncthreads();
    // stage 4 planes of 128x32 (8KB each); per wave per plane: 2 x 16-row gld16
#pragma unroll
    for (int i = 0; i < 2; ++i) {
      int rr = wave * 32 + i * 16 + (lane >> 2);        // 0..127 tile row
      int lofs = (wave * 32 + i * 16) * 32;             // wave-uniform elem base
      size_t gA = ((size_t)(m0 + rr) << 10) + (s << 5) + ((lane & 3) << 3);
      gld16(Xh + gA, Ah + lofs);
      gld16(Xl + gA, Al + lofs);
      size_t gB = ((size_t)(n0 + rr) << 11) + (s << 5) + ((lane & 3) << 3);
      gld16(Wt + gB, Bh + lofs);
      gld16(Wt + gB + 1024, Bl + lofs);
    }
    __syncthreads();
    const int seg = kq;                                 // 0..3 k-group of 8
    bf16x8 ah[4], al[4], bh[4], bl[4];
#pragma unroll
    for (int i = 0; i < 4; ++i) {
      int ar = wr * 64 + i * 16 + l15;
      int addr = ar * 32 + ((seg ^ ((ar >> 1) & 3)) << 3);
      ah[i] = *(const bf16x8*)&Ah[addr];
      al[i] = *(const bf16x8*)&Al[addr];
    }
#pragma unroll
    for (int j = 0; j < 4; ++j) {
      int br = wc * 64 + j * 16 + l15;
      int addr = br * 32 + ((seg ^ ((br >> 1) & 3)) << 3);
      bh[j] = *(const bf16x8*)&Bh[addr];
      bl[j] = *(const bf16x8*)&Bl[addr];
    }
#pragma unroll
    for (int i = 0; i < 4; ++i)
#pragma unroll
      for (int j = 0; j < 4; ++j) {
        acc[i][j] = __builtin_amdgcn_mfma_f32_16x16x32_bf16(ah[i], bh[j], acc[i][j], 0, 0, 0);
        acc[i][j] = __builtin_amdgcn_mfma_f32_16x16x32_bf16(al[i], bh[j], acc[i][j], 0, 0, 0);
        acc[i][j] = __builtin_amdgcn_mfma_f32_16x16x32_bf16(ah[i], bl[j], acc[i][j], 0, 0, 0);
      }
  }
#pragma unroll
  for (int i = 0; i < 4; ++i)
#pragma unroll
    for (int j = 0; j < 4; ++j) {
      int n = n0 + wc * 64 + j * 16 + l15;
      int tb = m0 + wr * 64 + i * 16 + kq * 4;
      float4 v = make_float4(acc[i][j][0] + bval[j], acc[i][j][1] + bval[j],
                             acc[i][j][2] + bval[j], acc[i][j][3] + bval[j]);
      *(float4*)&Out[(size_t)n * ldT + tb] = v;
    }
}

// ---------------- K2: packed dual FFT (re=q, im=k) + cross-spectrum ------------
// grid (8 dgroups, 16 heads, nbatch); 8 dims per block via 4 dual-FFT passes.
// T14 async-stage: next pass's 32 KB prefetched into registers before the FFT.
__global__ __launch_bounds__(256) void fftcorr_k(
    const float* __restrict__ Qt, const float* __restrict__ Kt,
    float* __restrict__ Pat, float2* __restrict__ Ppart, int ld)
{
  const int dg = blockIdx.x, h = blockIdx.y, b = blockIdx.z;
  const size_t bofs = (size_t)b * SS;
  __shared__ float2 z0[2048];
  __shared__ float2 z1[2048];
  __shared__ float2 tw[1024];
  const int tid = threadIdx.x;
  build_tw(tw, tid);
  float prr[8], pii[8];
#pragma unroll
  for (int l = 0; l < 8; ++l) { prr[l] = 0.f; pii[l] = 0.f; }

  float2 rq0[4], rk0[4], rq1[4], rk1[4];
  {
    const int n = h * 64 + dg * 8;
    const float2* q0 = (const float2*)(Qt + (size_t)n * ld + bofs);
    const float2* k0 = (const float2*)(Kt + (size_t)n * ld + bofs);
    const float2* q1 = (const float2*)(Qt + (size_t)(n + 1) * ld + bofs);
    const float2* k1 = (const float2*)(Kt + (size_t)(n + 1) * ld + bofs);
#pragma unroll
    for (int l = 0; l < 4; ++l) {
      int t2 = tid + l * 256;
      rq0[l] = q0[t2]; rk0[l] = k0[t2]; rq1[l] = q1[t2]; rk1[l] = k1[t2];
    }
  }

  for (int dd = 0; dd < 4; ++dd) {
    __syncthreads();                        // prev unpack done reading z
#pragma unroll
    for (int l = 0; l < 4; ++l) {
      int t2 = tid + l * 256;
      int t = 2 * t2;
      int rv = __brev((unsigned)t) >> 21;   // < 1024 (t even); odd sample -> rv+1024
      int zia = XS(rv);
      int zib = XS(rv + 1024);              // NOT zia+1024 for this swizzle!
      z0[zia] = make_float2(rq0[l].x, rk0[l].x);
      z0[zib] = make_float2(rq0[l].y, rk0[l].y);
      z1[zia] = make_float2(rq1[l].x, rk1[l].x);
      z1[zib] = make_float2(rq1[l].y, rk1[l].y);
    }
    if (dd < 3) {                           // async prefetch next pass into regs
      const int n = h * 64 + dg * 8 + (dd + 1) * 2;
      const float2* q0 = (const float2*)(Qt + (size_t)n * ld + bofs);
      const float2* k0 = (const float2*)(Kt + (size_t)n * ld + bofs);
      const float2* q1 = (const float2*)(Qt + (size_t)(n + 1) * ld + bofs);
      const float2* k1 = (const float2*)(Kt + (size_t)(n + 1) * ld + bofs);
#pragma unroll
      for (int l = 0; l < 4; ++l) {
        int t2 = tid + l * 256;
        rq0[l] = q0[t2]; rk0[l] = k0[t2]; rq1[l] = q1[t2]; rk1[l] = k1[t2];
      }
    }
    __syncthreads();
    fft2048x2_lds<1>(z0, z1, tw, tid);
    // unpack two real spectra per buffer; accumulate Qf * conj(Kf)
#pragma unroll
    for (int l = 0; l < 8; ++l) {
      int f = tid + l * 256;
      int fc = (2048 - f) & 2047;
#pragma unroll
      for (int s = 0; s < 2; ++s) {
        const float2* z = s ? z1 : z0;
        float2 Z = z[XS(f)];
        float2 Zc = z[XS(fc)];
        float Zcr = Zc.x, Zci = -Zc.y;
        float Qr = 0.5f * (Z.x + Zcr), Qi = 0.5f * (Z.y + Zci);
        float Kr = 0.5f * (Z.y - Zci), Ki = -0.5f * (Z.x - Zcr);
        prr[l] += Qr * Kr + Qi * Ki;
        pii[l] += Qi * Kr - Qr * Ki;
      }
    }
  }
  if (Ppart) {
    float2* Pp = Ppart + ((size_t)dg * 64 + (size_t)b * SH + h) * 2048;
#pragma unroll
    for (int l = 0; l < 8; ++l) {
      int f = tid + l * 256;
      Pp[f] = make_float2(prr[l], pii[l]);
    }
  } else {
    float* Pb = Pat;                          // caller pre-offsets per batch
#pragma unroll
    for (int l = 0; l < 8; ++l) {
      int f = tid + l * 256;
      atomicAdd(&Pb[((size_t)h * SS + f) * 2 + 0], prr[l]);
      atomicAdd(&Pb[((size_t)h * SS + f) * 2 + 1], pii[l]);
    }
  }
}

// ---------------- K3: inverse FFT + byte-radix top-409 + softmax, per (b,h) ----
// nparts>0: sum nparts partial spectra slices; else read pre-reduced P.
__global__ __launch_bounds__(256) void ifft_topk_k(
    const float* __restrict__ P, const float2* __restrict__ Ppart, int nparts,
    int* __restrict__ sidx, float* __restrict__ sw)
{
  const int bh = blockIdx.x;
  __shared__ float2 z[2048];
  __shared__ float2 tw[1024];
  __shared__ unsigned keys[2048];
  __shared__ int el_i[KTOP];
  __shared__ float el_w[KTOP];
  __shared__ int hist[256];
  __shared__ int scan_sh[256];
  __shared__ int wtot[4];
  __shared__ int cnt2, tiecnt, sel_v;
  __shared__ unsigned kmax_sh;
  __shared__ float Zsh;
  const int tid = threadIdx.x;
  const int lane = tid & 63, wv = tid >> 6;
  const float SCL = 1.0f / (2048.0f * 512.0f);   // 1/N * 1/(dh*sqrt(dh))

  build_tw(tw, tid);
  if (tid == 0) { cnt2 = 0; tiecnt = 0; kmax_sh = 0u; Zsh = 0.f; }
#pragma unroll
  for (int l = 0; l < 8; ++l) {
    int f = tid + l * 256;
    int rv = __brev((unsigned)f) >> 21;
    float2 acc;
    if (nparts > 0) {
      acc = make_float2(0.f, 0.f);
      for (int g = 0; g < nparts; ++g) {
        float2 v = Ppart[((size_t)g * 64 + bh) * 2048 + f];
        acc.x += v.x; acc.y += v.y;
      }
    } else {
      acc = ((const float2*)P)[(size_t)bh * SS + f];
    }
    z[XS(rv)] = acc;
  }
  __syncthreads();
  fft2048_lds<-1>(z, tw, tid);

  unsigned lm = 0u;
#pragma unroll
  for (int l = 0; l < 8; ++l) {
    int i = tid + l * 256;
    float v = z[XS(i)].x * SCL;
    z[XS(i)].x = v;
    unsigned u = __float_as_uint(v);
    unsigned k = (u & 0x80000000u) ? ~u : (u | 0x80000000u);
    keys[i] = k;
    lm = max(lm, k);
  }
  atomicMax(&kmax_sh, lm);
  __syncthreads();

  unsigned prefix = 0u;
  int remaining = KTOP;
  for (int p = 3; p >= 0; --p) {
    hist[tid] = 0;
    __syncthreads();
    unsigned mask_hi = (p == 3) ? 0u : (0xFFFFFFFFu << ((p + 1) * 8));
#pragma unroll
    for (int l = 0; l < 8; ++l) {
      unsigned k = keys[tid + l * 256];
      if ((k & mask_hi) == prefix) atomicAdd(&hist[(k >> (p * 8)) & 255], 1);
    }
    __syncthreads();
    // inclusive SUFFIX scan of hist: wave-level shfl + cross-wave combine
    int v = hist[tid];
#pragma unroll
    for (int off2 = 1; off2 < 64; off2 <<= 1) {
      int t = __shfl_down(v, off2);
      if (lane + off2 < 64) v += t;
    }
    if (lane == 0) wtot[wv] = v;
    __syncthreads();
    for (int w = wv + 1; w < 4; ++w) v += wtot[w];
    scan_sh[tid] = v;
    __syncthreads();
    if (scan_sh[tid] >= remaining && (tid == 255 || scan_sh[tid + 1] < remaining))
      sel_v = tid;
    __syncthreads();
    int vsel = sel_v;
    int above = (vsel == 255) ? 0 : scan_sh[vsel + 1];
    remaining -= above;
    prefix |= ((unsigned)vsel) << (p * 8);
    __syncthreads();
  }
  const unsigned T = prefix;
  unsigned km = kmax_sh;
  float vmax = __uint_as_float((km & 0x80000000u) ? (km ^ 0x80000000u) : ~km);

#pragma unroll
  for (int l = 0; l < 8; ++l) {
    int i = tid + l * 256;
    unsigned k = keys[i];
    if (k > T) {
      int pos = atomicAdd(&cnt2, 1);
      el_i[pos] = i;
      el_w[pos] = expf(z[XS(i)].x - vmax);
    } else if (k == T) {
      atomicAdd(&tiecnt, 1);
    }
  }
  __syncthreads();
  int need = KTOP - cnt2;
  if (tiecnt == need) {
#pragma unroll
    for (int l = 0; l < 8; ++l) {
      int i = tid + l * 256;
      if (keys[i] == T) {
        int pos = atomicAdd(&cnt2, 1);
        el_i[pos] = i;
        el_w[pos] = expf(z[XS(i)].x - vmax);
      }
    }
  } else if (tid == 0) {
    int pos = cnt2;
    for (int i = 0; i < SS && pos < KTOP; ++i)
      if (keys[i] == T) { el_i[pos] = i; el_w[pos] = expf(z[XS(i)].x - vmax); ++pos; }
  }
  __syncthreads();
  float zs = 0.f;
  for (int l = tid; l < KTOP; l += 256) zs += el_w[l];
  atomicAdd(&Zsh, zs);
  __syncthreads();
  float invZ = 1.0f / Zsh;
  for (int l = tid; l < KTOP; l += 256) {
    sidx[bh * KTOP + l] = el_i[l];
    sw[bh * KTOP + l]   = el_w[l] * invZ;
  }
}

// ---------------- K4: xbar partials: xpart[sl][bh][:] = sum_slice w*xv[b,idx,:] -
// xpart!=null: plain coalesced stores (no atomics); else atomicAdd into xbar.
__global__ __launch_bounds__(256) void xbar_k(
    const int* __restrict__ sidx, const float* __restrict__ sw,
    const float* __restrict__ xv, float* __restrict__ xbar,
    float* __restrict__ xpart)
{
  const int bh = blockIdx.x, b = bh >> 4, sl = blockIdx.y;
  const int r0 = sl * KPS;
  const int nr = min(KTOP - r0, KPS);
  __shared__ int il[KPS];
  __shared__ float wl[KPS];
  const int tid = threadIdx.x;
  if (tid < KPS) {
    il[tid] = (tid < nr) ? sidx[bh * KTOP + r0 + tid] : 0;
    wl[tid] = (tid < nr) ? sw[bh * KTOP + r0 + tid] : 0.f;
  }
  __syncthreads();
  const float4* xv4 = (const float4*)xv;
  float4 acc = make_float4(0.f, 0.f, 0.f, 0.f);
#pragma unroll 4
  for (int r = 0; r < KPS; ++r) {
    float w = wl[r];
    float4 v = xv4[(size_t)(b * SS + il[r]) * 256 + tid];
    acc.x += w * v.x; acc.y += w * v.y; acc.z += w * v.z; acc.w += w * v.w;
  }
  if (xpart) {
    ((float4*)(xpart + ((size_t)sl * 64 + bh) * 1024))[tid] = acc;
  } else {
    float* dst = xbar + (size_t)bh * 1024 + tid * 4;
    atomicAdd(dst + 0, acc.x); atomicAdd(dst + 1, acc.y);
    atomicAdd(dst + 2, acc.z); atomicAdd(dst + 3, acc.w);
  }
}

// ---------------- K5a: init attended=bv, outrow=bo -----------------------------
__global__ __launch_bounds__(256) void initbias_k(
    const float* __restrict__ bv, const float* __restrict__ bo,
    float* __restrict__ att, float* __restrict__ orow)
{
  int i = blockIdx.x * 256 + threadIdx.x;   // < 8192
  if (i < 4096) att[i] = bv[i & 1023];
  else          orow[i - 4096] = bo[i & 1023];
}

// ---------------- K5: attended[b,j] += sum_i xbar[b,j/64,i]*wv[i,j] ------------
// nsl>0: sum nsl xpart slices while loading xs (L2-hot); else read xbar.
__global__ __launch_bounds__(256) void attend_k(
    const float* __restrict__ xbar, const float* __restrict__ xpart, int nsl,
    const float* __restrict__ wv, float* __restrict__ att)
{
  const int b = blockIdx.y, i0 = blockIdx.x * 64;
  __shared__ float xs[16 * 64];
  const int tid = threadIdx.x;
#pragma unroll
  for (int l = 0; l < 4; ++l) {
    int f = tid + l * 256;
    int hh = f >> 6, ii = i0 + (f & 63);
    float s;
    if (nsl > 0) {
      s = 0.f;
      for (int g = 0; g < nsl; ++g)
        s += xpart[((size_t)g * 64 + b * 16 + hh) * 1024 + ii];
    } else {
      s = xbar[(size_t)(b * 16 + hh) * 1024 + ii];
    }
    xs[f] = s;
  }
  __syncthreads();
  const float4* wv4 = (const float4*)wv;
  const int h = tid >> 4;
  float4 acc = make_float4(0.f, 0.f, 0.f, 0.f);
  for (int m = 0; m < 64; ++m) {
    float xvs = xs[h * 64 + m];
    float4 w = wv4[(size_t)(i0 + m) * 256 + tid];
    acc.x += xvs * w.x; acc.y += xvs * w.y; acc.z += xvs * w.z; acc.w += xvs * w.w;
  }
  float* dst = att + (size_t)b * 1024 + tid * 4;
  atomicAdd(dst + 0, acc.x); atomicAdd(dst + 1, acc.y);
  atomicAdd(dst + 2, acc.z); atomicAdd(dst + 3, acc.w);
}

// ---------------- K6: outrow[b,n] += sum_m att[b,m]*wo[m,n] --------------------
__global__ __launch_bounds__(256) void oproj_k(
    const float* __restrict__ att, const float* __restrict__ wo,
    float* __restrict__ orow)
{
  const int b = blockIdx.y, m0 = blockIdx.x * 64;
  __shared__ float as_[64];
  const int tid = threadIdx.x;
  if (tid < 64) as_[tid] = att[(size_t)b * 1024 + m0 + tid];
  __syncthreads();
  const float4* wo4 = (const float4*)wo;
  float4 acc = make_float4(0.f, 0.f, 0.f, 0.f);
  for (int m = 0; m < 64; ++m) {
    float a = as_[m];
    float4 w = wo4[(size_t)(m0 + m) * 256 + tid];
    acc.x += a * w.x; acc.y += a * w.y; acc.z += a * w.z; acc.w += a * w.w;
  }
  float* dst = orow + (size_t)b * 1024 + tid * 4;
  atomicAdd(dst + 0, acc.x); atomicAdd(dst + 1, acc.y);
  atomicAdd(dst + 2, acc.z); atomicAdd(dst + 3, acc.w);
}

// ---------------- K7: broadcast outrow across S --------------------------------
__global__ __launch_bounds__(256) void bcast_k(
    const float* __restrict__ orow, float* __restrict__ out)
{
  int idx = blockIdx.x * 256 + threadIdx.x;           // float4 index
  const float4* o4 = (const float4*)orow;
  ((float4*)out)[idx] = o4[((idx >> 19) << 8) | (idx & 255)];
}

extern "C" void kernel_launch(void* const* d_in, const int* in_sizes, int n_in,
                              void* d_out, int out_size, void* d_ws, size_t ws_size,
                              hipStream_t stream) {
  (void)in_sizes; (void)n_in; (void)out_size;
  const float* xq = (const float*)d_in[0];
  const float* xk = (const float*)d_in[1];
  const float* xv = (const float*)d_in[2];
  const float* wq = (const float*)d_in[3];
  const float* bq = (const float*)d_in[4];
  const float* wk = (const float*)d_in[5];
  const float* bk = (const float*)d_in[6];
  const float* wv = (const float*)d_in[7];
  const float* bv = (const float*)d_in[8];
  const float* wo = (const float*)d_in[9];
  const float* bo = (const float*)d_in[10];
  float* out = (float*)d_out;

  // ---- small scratch (always in d_ws) ----
  char* base = (char*)d_ws;
  float* P = (float*)base;                     // B*H*S complex = 1 MB (fallback)
  size_t off = (size_t)SB * SH * SS * 2 * 4;
  int*   sidx = (int*)  (base + off); off += (size_t)SB * SH * KTOP * 4;
  float* sw   = (float*)(base + off); off += (size_t)SB * SH * KTOP * 4;
  float* xbar = (float*)(base + off); off += (size_t)SB * SH * SD * 4;
  float* att  = (float*)(base + off); off += (size_t)SB * SD * 4;
  float* orow = (float*)(base + off); off += (size_t)SB * SD * 4;

  // big-path layout in d_ws (ws poison fill shows 256 MiB available)
  size_t big0 = (off + 1048575) & ~(size_t)1048575;    // 1 MB align
  const size_t SZ_X = (size_t)SB * SS * SD * 2;        // 16 MB bf16 per split buf
  const size_t SZ_T = (size_t)SD * SB * SS * 4;        // 32 MB fp32 Qt/Kt
  const size_t SZ_W = (size_t)SD * 2048 * 2;           // 4 MB Wt
  const size_t SZ_P = (size_t)8 * 64 * 2048 * 8;       // 8 MB partial spectra
  const size_t SZ_XP = (size_t)KSL * 64 * 1024 * 4;    // 2 MB xbar partials
  size_t need_big = big0 + 4 * SZ_X + 2 * SZ_T + 2 * SZ_W + SZ_P + SZ_XP;

  if (ws_size >= need_big) {
    // ---------- big path: de-batched, no global atomics anywhere ----------
    char* bb = base + big0;
    short* Xqh = (short*)(bb);
    short* Xql = (short*)(bb + SZ_X);
    short* Xkh = (short*)(bb + 2 * SZ_X);
    short* Xkl = (short*)(bb + 3 * SZ_X);
    float* Qt  = (float*)(bb + 4 * SZ_X);
    float* Kt  = (float*)(bb + 4 * SZ_X + SZ_T);
    short* Wqt = (short*)(bb + 4 * SZ_X + 2 * SZ_T);
    short* Wkt = (short*)(bb + 4 * SZ_X + 2 * SZ_T + SZ_W);
    float2* Pp = (float2*)(bb + 4 * SZ_X + 2 * SZ_T + 2 * SZ_W);
    float* Xpart = (float*)(bb + 4 * SZ_X + 2 * SZ_T + 2 * SZ_W + SZ_P);

    splitwt_k<<<dim3(16, 16, 2), 256, 0, stream>>>(wq, wk, Wqt, Wkt);
    splitx2_k<<<dim3(SB * SS / 2, 2), 256, 0, stream>>>(xq, xk, Xqh, Xql, Xkh, Xkl);
    projm_k<<<dim3(8, SB * SS / 128, 2), 256, 0, stream>>>(
        Xqh, Xql, Wqt, bq, Qt, Xkh, Xkl, Wkt, bk, Kt, SB * SS);
    fftcorr_k<<<dim3(8, 16, SB), 256, 0, stream>>>(Qt, Kt, nullptr, Pp, SB * SS);
    ifft_topk_k<<<dim3(SB * SH), 256, 0, stream>>>(P, Pp, 8, sidx, sw);
    xbar_k<<<dim3(SB * SH, KSL), 256, 0, stream>>>(sidx, sw, xv, nullptr, Xpart);
    initbias_k<<<dim3(32), 256, 0, stream>>>(bv, bo, att, orow);
    attend_k<<<dim3(16, SB), 256, 0, stream>>>(nullptr, Xpart, KSL, wv, att);
  } else {
    // ---------- fallback: per-batch, atomic accumulate, scratch in d_out ----------
    char* ob = (char*)d_out;
    float* Qt  = (float*)(ob);                   // 8 MB [n][2048]
    float* Kt  = (float*)(ob + ( 8u << 20));     // 8 MB
    short* Wqt = (short*)(ob + (16u << 20));     // 4 MB
    short* Wkt = (short*)(ob + (20u << 20));     // 4 MB
    short* Xh  = (short*)(ob + (24u << 20));     // 4 MB per-batch split (hi)
    short* Xl  = (short*)(ob + (28u << 20));     // 4 MB (lo)

    hipMemsetAsync(P, 0, (size_t)SB * SH * SS * 2 * sizeof(float), stream);
    hipMemsetAsync(xbar, 0, (size_t)SB * SH * SD * sizeof(float), stream);
    splitwt_k<<<dim3(16, 16, 2), 256, 0, stream>>>(wq, wk, Wqt, Wkt);
    for (int b = 0; b < SB; ++b) {
      const float* xqb = xq + (size_t)b * SS * SD;
      const float* xkb = xk + (size_t)b * SS * SD;
      splitx2_k<<<dim3(SS / 2, 1), 256, 0, stream>>>(xqb, xqb, Xh, Xl, Xh, Xl);
      projm_k<<<dim3(8, SS / 128, 1), 256, 0, stream>>>(
          Xh, Xl, Wqt, bq, Qt, Xh, Xl, Wqt, bq, Qt, SS);
      splitx2_k<<<dim3(SS / 2, 1), 256, 0, stream>>>(xkb, xkb, Xh, Xl, Xh, Xl);
      projm_k<<<dim3(8, SS / 128, 1), 256, 0, stream>>>(
          Xh, Xl, Wkt, bk, Kt, Xh, Xl, Wkt, bk, Kt, SS);
      fftcorr_k<<<dim3(8, 16, 1), 256, 0, stream>>>(
          Qt, Kt, P + (size_t)b * SH * SS * 2, nullptr, SS);
    }
    ifft_topk_k<<<dim3(SB * SH), 256, 0, stream>>>(P, nullptr, 0, sidx, sw);
    xbar_k<<<dim3(SB * SH, KSL), 256, 0, stream>>>(sidx, sw, xv, xbar, nullptr);
    initbias_k<<<dim3(32), 256, 0, stream>>>(bv, bo, att, orow);
    attend_k<<<dim3(16, SB), 256, 0, stream>>>(xbar, nullptr, 0, wv, att);
  }

  oproj_k<<<dim3(16, SB), 256, 0, stream>>>(att, wo, orow);
  bcast_k<<<dim3(8192), 256, 0, stream>>>(orow, out);
}

// Round 10
// 350.743 us; speedup vs baseline: 1.0887x; 1.0887x over previous
//
#include <hip/hip_runtime.h>
#include <math.h>

#define SB 4
#define SS 2048
#define SD 1024
#define SH 16
#define KTOP 409   // max(2048//5, 1)
#define KSL 8      // xbar split-K slices
#define KPS 52     // ceil(KTOP/KSL)

typedef float f32x4  __attribute__((ext_vector_type(4)));
typedef short bf16x8 __attribute__((ext_vector_type(8)));
typedef short s16x4  __attribute__((ext_vector_type(4)));

__device__ __forceinline__ short f2bf(float x) {
  unsigned u = __float_as_uint(x);
  u += 0x7fff + ((u >> 16) & 1);           // RNE
  return (short)(u >> 16);
}
__device__ __forceinline__ float bf2f(short s) {
  return __uint_as_float(((unsigned)(unsigned short)s) << 16);
}

// async global->LDS, 16B per lane; LDS base must be wave-uniform (HW adds lane*16B)
__device__ __forceinline__ void gld16(const void* g, void* l) {
  __builtin_amdgcn_global_load_lds(
      (const __attribute__((address_space(1))) void*)g,
      (__attribute__((address_space(3))) void*)l, 16, 0, 0);
}

// XOR bank-swizzle for FFT LDS arrays (float2 granularity: bank-pair = idx mod 16).
// Folds BOTH upper nibbles into the bank bits. NOTE: XS(i+1024) != XS(i)+1024
// for this swizzle — always compute XS() explicitly per index.
#define XS(i) ((i) ^ ((((i) >> 4) ^ ((i) >> 8)) & 15))

// ---- 2048-pt FFT cores: radix-2 stage + 5 fused radix-4 DIT stages ------------
template<int SIGN>
__device__ __forceinline__ void fft2048_lds(float2* z, const float2* tw, int tid) {
#pragma unroll
  for (int l = 0; l < 4; ++l) {
    int bf = tid + l * 256;                 // 0..1023
    int i0 = XS(2 * bf), i1 = XS(2 * bf + 1);
    float2 a = z[i0], b = z[i1];
    z[i0] = make_float2(a.x + b.x, a.y + b.y);
    z[i1] = make_float2(a.x - b.x, a.y - b.y);
  }
  __syncthreads();
#pragma unroll
  for (int lq = 1; lq <= 9; lq += 2) {
    const int q = 1 << lq;
#pragma unroll
    for (int l = 0; l < 2; ++l) {
      int bf = tid + l * 256;               // 0..511
      int p = bf & (q - 1);
      int base = ((bf >> lq) << (lq + 2)) + p;
      int e1 = p << (9 - lq);
      int e2 = e1 << 1;
      int e3 = e1 * 3;
      float2 w1 = tw[XS(e1)];
      float2 w2 = tw[XS(e2)];
      float s3 = 1.f; int e3w = e3;
      if (e3 >= 1024) { e3w = e3 - 1024; s3 = -1.f; }
      float2 w3 = tw[XS(e3w)]; w3.x *= s3; w3.y *= s3;
      float2 t0 = z[XS(base)];
      float2 vb = z[XS(base + 2 * q)];      // j=1
      float2 vc = z[XS(base + q)];          // j=2
      float2 vd = z[XS(base + 3 * q)];      // j=3
      float w1i = SIGN * w1.y, w2i = SIGN * w2.y, w3i = SIGN * w3.y;
      float2 t1 = make_float2(vb.x * w1.x - vb.y * w1i, vb.x * w1i + vb.y * w1.x);
      float2 t2 = make_float2(vc.x * w2.x - vc.y * w2i, vc.x * w2i + vc.y * w2.x);
      float2 t3 = make_float2(vd.x * w3.x - vd.y * w3i, vd.x * w3i + vd.y * w3.x);
      float2 s02 = make_float2(t0.x + t2.x, t0.y + t2.y);
      float2 d02 = make_float2(t0.x - t2.x, t0.y - t2.y);
      float2 s13 = make_float2(t1.x + t3.x, t1.y + t3.y);
      float2 d13 = make_float2(t1.x - t3.x, t1.y - t3.y);
      float2 r13 = make_float2(SIGN * d13.y, -SIGN * d13.x);
      z[XS(base)]         = make_float2(s02.x + s13.x, s02.y + s13.y);
      z[XS(base + q)]     = make_float2(d02.x + r13.x, d02.y + r13.y);
      z[XS(base + 2 * q)] = make_float2(s02.x - s13.x, s02.y - s13.y);
      z[XS(base + 3 * q)] = make_float2(d02.x - r13.x, d02.y - r13.y);
    }
    __syncthreads();
  }
}

// Dual-buffer variant: two independent FFTs advance in lockstep under ONE sync
// ladder; twiddle index math + loads shared between the two butterflies.
template<int SIGN>
__device__ __forceinline__ void fft2048x2_lds(
    float2* __restrict__ z0, float2* __restrict__ z1,
    const float2* tw, int tid)
{
#pragma unroll
  for (int l = 0; l < 4; ++l) {
    int bf = tid + l * 256;                 // 0..1023
    int i0 = XS(2 * bf), i1 = XS(2 * bf + 1);
    float2 a0 = z0[i0], b0 = z0[i1];
    float2 a1 = z1[i0], b1 = z1[i1];
    z0[i0] = make_float2(a0.x + b0.x, a0.y + b0.y);
    z0[i1] = make_float2(a0.x - b0.x, a0.y - b0.y);
    z1[i0] = make_float2(a1.x + b1.x, a1.y + b1.y);
    z1[i1] = make_float2(a1.x - b1.x, a1.y - b1.y);
  }
  __syncthreads();
#pragma unroll
  for (int lq = 1; lq <= 9; lq += 2) {
    const int q = 1 << lq;
#pragma unroll
    for (int l = 0; l < 2; ++l) {
      int bf = tid + l * 256;               // 0..511
      int p = bf & (q - 1);
      int base = ((bf >> lq) << (lq + 2)) + p;
      int e1 = p << (9 - lq);
      int e2 = e1 << 1;
      int e3 = e1 * 3;
      float2 w1 = tw[XS(e1)];
      float2 w2 = tw[XS(e2)];
      float s3 = 1.f; int e3w = e3;
      if (e3 >= 1024) { e3w = e3 - 1024; s3 = -1.f; }
      float2 w3 = tw[XS(e3w)]; w3.x *= s3; w3.y *= s3;
      float w1i = SIGN * w1.y, w2i = SIGN * w2.y, w3i = SIGN * w3.y;
      const int ia = XS(base), ib = XS(base + 2 * q),
                ic = XS(base + q), id = XS(base + 3 * q);
#pragma unroll
      for (int s = 0; s < 2; ++s) {
        float2* z = s ? z1 : z0;
        float2 t0 = z[ia];
        float2 vb = z[ib];                  // j=1
        float2 vc = z[ic];                  // j=2
        float2 vd = z[id];                  // j=3
        float2 t1 = make_float2(vb.x * w1.x - vb.y * w1i, vb.x * w1i + vb.y * w1.x);
        float2 t2 = make_float2(vc.x * w2.x - vc.y * w2i, vc.x * w2i + vc.y * w2.x);
        float2 t3 = make_float2(vd.x * w3.x - vd.y * w3i, vd.x * w3i + vd.y * w3.x);
        float2 s02 = make_float2(t0.x + t2.x, t0.y + t2.y);
        float2 d02 = make_float2(t0.x - t2.x, t0.y - t2.y);
        float2 s13 = make_float2(t1.x + t3.x, t1.y + t3.y);
        float2 d13 = make_float2(t1.x - t3.x, t1.y - t3.y);
        float2 r13 = make_float2(SIGN * d13.y, -SIGN * d13.x);
        z[ia] = make_float2(s02.x + s13.x, s02.y + s13.y);
        z[ic] = make_float2(d02.x + r13.x, d02.y + r13.y);
        z[ib] = make_float2(s02.x - s13.x, s02.y - s13.y);
        z[id] = make_float2(d02.x - r13.x, d02.y - r13.y);
      }
    }
    __syncthreads();
  }
}

// in-block twiddle table build: tw[XS(j)] = exp(-2pi i j/2048), hidden under loads
__device__ __forceinline__ void build_tw(float2* tw, int tid) {
  for (int j = tid; j < 1024; j += 256) {
    float a = 6.2831853071795864769f * (float)j / 2048.0f;
    tw[XS(j)] = make_float2(cosf(a), -sinf(a));
  }
}

// ---------------- P0: transpose + split W[k][n] -> Wt[n][{hi:0..1023|lo:1024..2047}]
__global__ __launch_bounds__(256) void splitwt_k(
    const float* __restrict__ wq, const float* __restrict__ wk,
    short* __restrict__ wqt, short* __restrict__ wkt)
{
  const float* W = blockIdx.z ? wk : wq;
  short* Wt = blockIdx.z ? wkt : wqt;
  const int n0 = blockIdx.x * 64, k0 = blockIdx.y * 64;
  __shared__ float T[64][65];
  const int tid = threadIdx.x;
#pragma unroll
  for (int l = 0; l < 4; ++l) {
    int idx = tid + l * 256;
    int r = idx >> 4, c4 = (idx & 15) << 2;
    float4 v = *(const float4*)&W[(size_t)(k0 + r) * SD + n0 + c4];
    T[r][c4 + 0] = v.x; T[r][c4 + 1] = v.y; T[r][c4 + 2] = v.z; T[r][c4 + 3] = v.w;
  }
  __syncthreads();
#pragma unroll
  for (int l = 0; l < 4; ++l) {
    int idx = tid + l * 256;
    int nr = idx >> 4, k4 = (idx & 15) << 2;
    s16x4 hi, lo;
#pragma unroll
    for (int j = 0; j < 4; ++j) {
      float x = T[k4 + j][nr];
      short hb = f2bf(x);
      hi[j] = hb; lo[j] = f2bf(x - bf2f(hb));
    }
    int ks = (((k4 >> 3) ^ (nr & 7)) << 3) | (k4 & 7);
    *(s16x4*)&Wt[(size_t)(n0 + nr) * 2048 + k0 + ks] = hi;
    *(s16x4*)&Wt[(size_t)(n0 + nr) * 2048 + 1024 + k0 + ks] = lo;
  }
}

// ---------------- P0b: split X rows -> Xh/Xl bf16, pre-swizzled ----------------
__global__ __launch_bounds__(256) void splitx2_k(
    const float* __restrict__ Xq, const float* __restrict__ Xk,
    short* __restrict__ Xqh, short* __restrict__ Xql,
    short* __restrict__ Xkh, short* __restrict__ Xkl)
{
  const int tid = threadIdx.x;
  const int row = blockIdx.x * 2 + (tid >> 7);
  const int G = tid & 127;                  // 8-elem group within the row
  const float* X = blockIdx.y ? Xk : Xq;
  short* Xh = blockIdx.y ? Xkh : Xqh;
  short* Xl = blockIdx.y ? Xkl : Xql;
  const float* src = X + ((size_t)row << 10) + (G << 3);
  float4 a = *(const float4*)src;
  float4 b = *(const float4*)(src + 4);
  float xs[8] = {a.x, a.y, a.z, a.w, b.x, b.y, b.z, b.w};
  bf16x8 hi, lo;
#pragma unroll
  for (int j = 0; j < 8; ++j) {
    short hb = f2bf(xs[j]);
    hi[j] = hb; lo[j] = f2bf(xs[j] - bf2f(hb));
  }
  int Gd = (G & 0x78) | ((G ^ row) & 7);    // swizzle group within 64-span
  size_t d = ((size_t)row << 10) + (Gd << 3);
  *(bf16x8*)&Xh[d] = hi;
  *(bf16x8*)&Xl[d] = lo;
}

// ---------------- K1: split-bf16 MFMA projection, 128x128 tile, BK=64 ----------
// grid (nb, mb, nz). XCD-locality remap: each XCD owns a contiguous supertile
// run with nb fastest -> A panel reused by 8 consecutive blocks on one XCD,
// B (Wt) stays L2-resident per XCD. Bijective for total%8==0.
// NOTE: BK=32 variant (R9) measured WORSE (117 vs 90 us): less MFMA work per
// barrier interval dominates any occupancy gain. Keep BK=64.
__global__ __launch_bounds__(256) void projm_k(
    const short* __restrict__ Xqh, const short* __restrict__ Xql,
    const short* __restrict__ Wq_, const float* __restrict__ bq_,
    float* __restrict__ Oq_,
    const short* __restrict__ Xkh, const short* __restrict__ Xkl,
    const short* __restrict__ Wk_, const float* __restrict__ bk_,
    float* __restrict__ Ok_, int ldT)
{
  const int total = gridDim.x * gridDim.y * gridDim.z;
  int g = blockIdx.x + gridDim.x * (blockIdx.y + gridDim.y * blockIdx.z);
  int t = ((total & 7) == 0) ? (((g & 7) * (total >> 3)) + (g >> 3)) : g;
  const int nb = t % gridDim.x;
  int tmp = t / gridDim.x;
  const int mb = tmp % gridDim.y;
  const int zb = tmp / gridDim.y;

  const short* Xh; const short* Xl; const short* Wt; const float* bias; float* Out;
  if (zb == 0) { Xh = Xqh; Xl = Xql; Wt = Wq_; bias = bq_; Out = Oq_; }
  else         { Xh = Xkh; Xl = Xkl; Wt = Wk_; bias = bk_; Out = Ok_; }
  const int n0 = nb * 128, m0 = mb * 128;
  __shared__ __align__(16) short Ah[128 * 64];
  __shared__ __align__(16) short Al[128 * 64];
  __shared__ __align__(16) short Bh[128 * 64];
  __shared__ __align__(16) short Bl[128 * 64];
  const int tid = threadIdx.x;
  const int wave = tid >> 6, lane = tid & 63, l15 = lane & 15, kq = lane >> 4;
  const int wr = wave >> 1, wc = wave & 1;
  const int sr = lane >> 3, sc = lane & 7;   // staging: row-in-8 / col-group
  f32x4 acc[4][4];
#pragma unroll
  for (int i = 0; i < 4; ++i)
#pragma unroll
    for (int j = 0; j < 4; ++j)
#pragma unroll
      for (int r = 0; r < 4; ++r) acc[i][j][r] = 0.f;
  float bval[4];
#pragma unroll
  for (int j = 0; j < 4; ++j) bval[j] = bias[n0 + wc * 64 + j * 16 + l15];

  for (int s = 0; s < 16; ++s) {
    __syncthreads();
#pragma unroll
    for (int l = 0; l < 4; ++l) {
      int rr = l * 32 + wave * 8 + sr;                  // 0..127 tile row
      int lofs = (l * 32 + wave * 8) * 64;              // wave-uniform LDS elem base
      size_t gA = ((size_t)(m0 + rr) << 10) + (s << 6) + (sc << 3);
      gld16(Xh + gA, Ah + lofs);
      gld16(Xl + gA, Al + lofs);
      size_t gB = ((size_t)(n0 + rr) << 11) + (s << 6) + (sc << 3);
      gld16(Wt + gB, Bh + lofs);
      gld16(Wt + gB + 1024, Bl + lofs);
    }
    __syncthreads();
#pragma unroll
    for (int ks = 0; ks < 2; ++ks) {
      int seg = ks * 4 + kq;
      bf16x8 ah[4], al[4], bh[4], bl[4];
#pragma unroll
      for (int i = 0; i < 4; ++i) {
        int ar = wr * 64 + i * 16 + l15;
        int addr = ar * 64 + ((seg ^ (ar & 7)) << 3);
        ah[i] = *(const bf16x8*)&Ah[addr];
        al[i] = *(const bf16x8*)&Al[addr];
      }
#pragma unroll
      for (int j = 0; j < 4; ++j) {
        int br = wc * 64 + j * 16 + l15;
        int addr = br * 64 + ((seg ^ (br & 7)) << 3);
        bh[j] = *(const bf16x8*)&Bh[addr];
        bl[j] = *(const bf16x8*)&Bl[addr];
      }
#pragma unroll
      for (int i = 0; i < 4; ++i)
#pragma unroll
        for (int j = 0; j < 4; ++j) {
          acc[i][j] = __builtin_amdgcn_mfma_f32_16x16x32_bf16(ah[i], bh[j], acc[i][j], 0, 0, 0);
          acc[i][j] = __builtin_amdgcn_mfma_f32_16x16x32_bf16(al[i], bh[j], acc[i][j], 0, 0, 0);
          acc[i][j] = __builtin_amdgcn_mfma_f32_16x16x32_bf16(ah[i], bl[j], acc[i][j], 0, 0, 0);
        }
    }
  }
#pragma unroll
  for (int i = 0; i < 4; ++i)
#pragma unroll
    for (int j = 0; j < 4; ++j) {
      int n = n0 + wc * 64 + j * 16 + l15;
      int tb = m0 + wr * 64 + i * 16 + kq * 4;
      float4 v = make_float4(acc[i][j][0] + bval[j], acc[i][j][1] + bval[j],
                             acc[i][j][2] + bval[j], acc[i][j][3] + bval[j]);
      *(float4*)&Out[(size_t)n * ldT + tb] = v;
    }
}

// ---------------- K2: packed dual FFT (re=q, im=k) + cross-spectrum ------------
// grid (8 dgroups, 16 heads, nbatch); 8 dims per block via 4 dual-FFT passes.
// T14 async-stage: next pass's 32 KB prefetched into registers before the FFT.
__global__ __launch_bounds__(256) void fftcorr_k(
    const float* __restrict__ Qt, const float* __restrict__ Kt,
    float* __restrict__ Pat, float2* __restrict__ Ppart, int ld)
{
  const int dg = blockIdx.x, h = blockIdx.y, b = blockIdx.z;
  const size_t bofs = (size_t)b * SS;
  __shared__ float2 z0[2048];
  __shared__ float2 z1[2048];
  __shared__ float2 tw[1024];
  const int tid = threadIdx.x;
  build_tw(tw, tid);
  float prr[8], pii[8];
#pragma unroll
  for (int l = 0; l < 8; ++l) { prr[l] = 0.f; pii[l] = 0.f; }

  float2 rq0[4], rk0[4], rq1[4], rk1[4];
  {
    const int n = h * 64 + dg * 8;
    const float2* q0 = (const float2*)(Qt + (size_t)n * ld + bofs);
    const float2* k0 = (const float2*)(Kt + (size_t)n * ld + bofs);
    const float2* q1 = (const float2*)(Qt + (size_t)(n + 1) * ld + bofs);
    const float2* k1 = (const float2*)(Kt + (size_t)(n + 1) * ld + bofs);
#pragma unroll
    for (int l = 0; l < 4; ++l) {
      int t2 = tid + l * 256;
      rq0[l] = q0[t2]; rk0[l] = k0[t2]; rq1[l] = q1[t2]; rk1[l] = k1[t2];
    }
  }

  for (int dd = 0; dd < 4; ++dd) {
    __syncthreads();                        // prev unpack done reading z
#pragma unroll
    for (int l = 0; l < 4; ++l) {
      int t2 = tid + l * 256;
      int t = 2 * t2;
      int rv = __brev((unsigned)t) >> 21;   // < 1024 (t even); odd sample -> rv+1024
      int zia = XS(rv);
      int zib = XS(rv + 1024);              // NOT zia+1024 for this swizzle!
      z0[zia] = make_float2(rq0[l].x, rk0[l].x);
      z0[zib] = make_float2(rq0[l].y, rk0[l].y);
      z1[zia] = make_float2(rq1[l].x, rk1[l].x);
      z1[zib] = make_float2(rq1[l].y, rk1[l].y);
    }
    if (dd < 3) {                           // async prefetch next pass into regs
      const int n = h * 64 + dg * 8 + (dd + 1) * 2;
      const float2* q0 = (const float2*)(Qt + (size_t)n * ld + bofs);
      const float2* k0 = (const float2*)(Kt + (size_t)n * ld + bofs);
      const float2* q1 = (const float2*)(Qt + (size_t)(n + 1) * ld + bofs);
      const float2* k1 = (const float2*)(Kt + (size_t)(n + 1) * ld + bofs);
#pragma unroll
      for (int l = 0; l < 4; ++l) {
        int t2 = tid + l * 256;
        rq0[l] = q0[t2]; rk0[l] = k0[t2]; rq1[l] = q1[t2]; rk1[l] = k1[t2];
      }
    }
    __syncthreads();
    fft2048x2_lds<1>(z0, z1, tw, tid);
    // unpack two real spectra per buffer; accumulate Qf * conj(Kf)
#pragma unroll
    for (int l = 0; l < 8; ++l) {
      int f = tid + l * 256;
      int fc = (2048 - f) & 2047;
#pragma unroll
      for (int s = 0; s < 2; ++s) {
        const float2* z = s ? z1 : z0;
        float2 Z = z[XS(f)];
        float2 Zc = z[XS(fc)];
        float Zcr = Zc.x, Zci = -Zc.y;
        float Qr = 0.5f * (Z.x + Zcr), Qi = 0.5f * (Z.y + Zci);
        float Kr = 0.5f * (Z.y - Zci), Ki = -0.5f * (Z.x - Zcr);
        prr[l] += Qr * Kr + Qi * Ki;
        pii[l] += Qi * Kr - Qr * Ki;
      }
    }
  }
  if (Ppart) {
    float2* Pp = Ppart + ((size_t)dg * 64 + (size_t)b * SH + h) * 2048;
#pragma unroll
    for (int l = 0; l < 8; ++l) {
      int f = tid + l * 256;
      Pp[f] = make_float2(prr[l], pii[l]);
    }
  } else {
    float* Pb = Pat;                          // caller pre-offsets per batch
#pragma unroll
    for (int l = 0; l < 8; ++l) {
      int f = tid + l * 256;
      atomicAdd(&Pb[((size_t)h * SS + f) * 2 + 0], prr[l]);
      atomicAdd(&Pb[((size_t)h * SS + f) * 2 + 1], pii[l]);
    }
  }
}

// ---------------- K3: inverse FFT + byte-radix top-409 + softmax, per (b,h) ----
// nparts>0: sum nparts partial spectra slices; else read pre-reduced P.
__global__ __launch_bounds__(256) void ifft_topk_k(
    const float* __restrict__ P, const float2* __restrict__ Ppart, int nparts,
    int* __restrict__ sidx, float* __restrict__ sw)
{
  const int bh = blockIdx.x;
  __shared__ float2 z[2048];
  __shared__ float2 tw[1024];
  __shared__ unsigned keys[2048];
  __shared__ int el_i[KTOP];
  __shared__ float el_w[KTOP];
  __shared__ int hist[256];
  __shared__ int scan_sh[256];
  __shared__ int wtot[4];
  __shared__ int cnt2, tiecnt, sel_v;
  __shared__ unsigned kmax_sh;
  __shared__ float Zsh;
  const int tid = threadIdx.x;
  const int lane = tid & 63, wv = tid >> 6;
  const float SCL = 1.0f / (2048.0f * 512.0f);   // 1/N * 1/(dh*sqrt(dh))

  build_tw(tw, tid);
  if (tid == 0) { cnt2 = 0; tiecnt = 0; kmax_sh = 0u; Zsh = 0.f; }
#pragma unroll
  for (int l = 0; l < 8; ++l) {
    int f = tid + l * 256;
    int rv = __brev((unsigned)f) >> 21;
    float2 acc;
    if (nparts > 0) {
      acc = make_float2(0.f, 0.f);
      for (int g = 0; g < nparts; ++g) {
        float2 v = Ppart[((size_t)g * 64 + bh) * 2048 + f];
        acc.x += v.x; acc.y += v.y;
      }
    } else {
      acc = ((const float2*)P)[(size_t)bh * SS + f];
    }
    z[XS(rv)] = acc;
  }
  __syncthreads();
  fft2048_lds<-1>(z, tw, tid);

  unsigned lm = 0u;
#pragma unroll
  for (int l = 0; l < 8; ++l) {
    int i = tid + l * 256;
    float v = z[XS(i)].x * SCL;
    z[XS(i)].x = v;
    unsigned u = __float_as_uint(v);
    unsigned k = (u & 0x80000000u) ? ~u : (u | 0x80000000u);
    keys[i] = k;
    lm = max(lm, k);
  }
  atomicMax(&kmax_sh, lm);
  __syncthreads();

  unsigned prefix = 0u;
  int remaining = KTOP;
  for (int p = 3; p >= 0; --p) {
    hist[tid] = 0;
    __syncthreads();
    unsigned mask_hi = (p == 3) ? 0u : (0xFFFFFFFFu << ((p + 1) * 8));
#pragma unroll
    for (int l = 0; l < 8; ++l) {
      unsigned k = keys[tid + l * 256];
      if ((k & mask_hi) == prefix) atomicAdd(&hist[(k >> (p * 8)) & 255], 1);
    }
    __syncthreads();
    // inclusive SUFFIX scan of hist: wave-level shfl + cross-wave combine
    int v = hist[tid];
#pragma unroll
    for (int off2 = 1; off2 < 64; off2 <<= 1) {
      int t = __shfl_down(v, off2);
      if (lane + off2 < 64) v += t;
    }
    if (lane == 0) wtot[wv] = v;
    __syncthreads();
    for (int w = wv + 1; w < 4; ++w) v += wtot[w];
    scan_sh[tid] = v;
    __syncthreads();
    if (scan_sh[tid] >= remaining && (tid == 255 || scan_sh[tid + 1] < remaining))
      sel_v = tid;
    __syncthreads();
    int vsel = sel_v;
    int above = (vsel == 255) ? 0 : scan_sh[vsel + 1];
    remaining -= above;
    prefix |= ((unsigned)vsel) << (p * 8);
    __syncthreads();
  }
  const unsigned T = prefix;
  unsigned km = kmax_sh;
  float vmax = __uint_as_float((km & 0x80000000u) ? (km ^ 0x80000000u) : ~km);

#pragma unroll
  for (int l = 0; l < 8; ++l) {
    int i = tid + l * 256;
    unsigned k = keys[i];
    if (k > T) {
      int pos = atomicAdd(&cnt2, 1);
      el_i[pos] = i;
      el_w[pos] = expf(z[XS(i)].x - vmax);
    } else if (k == T) {
      atomicAdd(&tiecnt, 1);
    }
  }
  __syncthreads();
  int need = KTOP - cnt2;
  if (tiecnt == need) {
#pragma unroll
    for (int l = 0; l < 8; ++l) {
      int i = tid + l * 256;
      if (keys[i] == T) {
        int pos = atomicAdd(&cnt2, 1);
        el_i[pos] = i;
        el_w[pos] = expf(z[XS(i)].x - vmax);
      }
    }
  } else if (tid == 0) {
    int pos = cnt2;
    for (int i = 0; i < SS && pos < KTOP; ++i)
      if (keys[i] == T) { el_i[pos] = i; el_w[pos] = expf(z[XS(i)].x - vmax); ++pos; }
  }
  __syncthreads();
  float zs = 0.f;
  for (int l = tid; l < KTOP; l += 256) zs += el_w[l];
  atomicAdd(&Zsh, zs);
  __syncthreads();
  float invZ = 1.0f / Zsh;
  for (int l = tid; l < KTOP; l += 256) {
    sidx[bh * KTOP + l] = el_i[l];
    sw[bh * KTOP + l]   = el_w[l] * invZ;
  }
}

// ---------------- K4: xbar partials: xpart[sl][bh][:] = sum_slice w*xv[b,idx,:] -
// xpart!=null: plain coalesced stores (no atomics); else atomicAdd into xbar.
__global__ __launch_bounds__(256) void xbar_k(
    const int* __restrict__ sidx, const float* __restrict__ sw,
    const float* __restrict__ xv, float* __restrict__ xbar,
    float* __restrict__ xpart)
{
  const int bh = blockIdx.x, b = bh >> 4, sl = blockIdx.y;
  const int r0 = sl * KPS;
  const int nr = min(KTOP - r0, KPS);
  __shared__ int il[KPS];
  __shared__ float wl[KPS];
  const int tid = threadIdx.x;
  if (tid < KPS) {
    il[tid] = (tid < nr) ? sidx[bh * KTOP + r0 + tid] : 0;
    wl[tid] = (tid < nr) ? sw[bh * KTOP + r0 + tid] : 0.f;
  }
  __syncthreads();
  const float4* xv4 = (const float4*)xv;
  float4 acc = make_float4(0.f, 0.f, 0.f, 0.f);
#pragma unroll 4
  for (int r = 0; r < KPS; ++r) {
    float w = wl[r];
    float4 v = xv4[(size_t)(b * SS + il[r]) * 256 + tid];
    acc.x += w * v.x; acc.y += w * v.y; acc.z += w * v.z; acc.w += w * v.w;
  }
  if (xpart) {
    ((float4*)(xpart + ((size_t)sl * 64 + bh) * 1024))[tid] = acc;
  } else {
    float* dst = xbar + (size_t)bh * 1024 + tid * 4;
    atomicAdd(dst + 0, acc.x); atomicAdd(dst + 1, acc.y);
    atomicAdd(dst + 2, acc.z); atomicAdd(dst + 3, acc.w);
  }
}

// ---------------- K5a: init attended=bv, outrow=bo -----------------------------
__global__ __launch_bounds__(256) void initbias_k(
    const float* __restrict__ bv, const float* __restrict__ bo,
    float* __restrict__ att, float* __restrict__ orow)
{
  int i = blockIdx.x * 256 + threadIdx.x;   // < 8192
  if (i < 4096) att[i] = bv[i & 1023];
  else          orow[i - 4096] = bo[i & 1023];
}

// ---------------- K5: attended[b,j] += sum_i xbar[b,j/64,i]*wv[i,j] ------------
// nsl>0: sum nsl xpart slices while loading xs (L2-hot); else read xbar.
__global__ __launch_bounds__(256) void attend_k(
    const float* __restrict__ xbar, const float* __restrict__ xpart, int nsl,
    const float* __restrict__ wv, float* __restrict__ att)
{
  const int b = blockIdx.y, i0 = blockIdx.x * 64;
  __shared__ float xs[16 * 64];
  const int tid = threadIdx.x;
#pragma unroll
  for (int l = 0; l < 4; ++l) {
    int f = tid + l * 256;
    int hh = f >> 6, ii = i0 + (f & 63);
    float s;
    if (nsl > 0) {
      s = 0.f;
      for (int g = 0; g < nsl; ++g)
        s += xpart[((size_t)g * 64 + b * 16 + hh) * 1024 + ii];
    } else {
      s = xbar[(size_t)(b * 16 + hh) * 1024 + ii];
    }
    xs[f] = s;
  }
  __syncthreads();
  const float4* wv4 = (const float4*)wv;
  const int h = tid >> 4;
  float4 acc = make_float4(0.f, 0.f, 0.f, 0.f);
  for (int m = 0; m < 64; ++m) {
    float xvs = xs[h * 64 + m];
    float4 w = wv4[(size_t)(i0 + m) * 256 + tid];
    acc.x += xvs * w.x; acc.y += xvs * w.y; acc.z += xvs * w.z; acc.w += xvs * w.w;
  }
  float* dst = att + (size_t)b * 1024 + tid * 4;
  atomicAdd(dst + 0, acc.x); atomicAdd(dst + 1, acc.y);
  atomicAdd(dst + 2, acc.z); atomicAdd(dst + 3, acc.w);
}

// ---------------- K6: outrow[b,n] += sum_m att[b,m]*wo[m,n] --------------------
__global__ __launch_bounds__(256) void oproj_k(
    const float* __restrict__ att, const float* __restrict__ wo,
    float* __restrict__ orow)
{
  const int b = blockIdx.y, m0 = blockIdx.x * 64;
  __shared__ float as_[64];
  const int tid = threadIdx.x;
  if (tid < 64) as_[tid] = att[(size_t)b * 1024 + m0 + tid];
  __syncthreads();
  const float4* wo4 = (const float4*)wo;
  float4 acc = make_float4(0.f, 0.f, 0.f, 0.f);
  for (int m = 0; m < 64; ++m) {
    float a = as_[m];
    float4 w = wo4[(size_t)(m0 + m) * 256 + tid];
    acc.x += a * w.x; acc.y += a * w.y; acc.z += a * w.z; acc.w += a * w.w;
  }
  float* dst = orow + (size_t)b * 1024 + tid * 4;
  atomicAdd(dst + 0, acc.x); atomicAdd(dst + 1, acc.y);
  atomicAdd(dst + 2, acc.z); atomicAdd(dst + 3, acc.w);
}

// ---------------- K7: broadcast outrow across S --------------------------------
__global__ __launch_bounds__(256) void bcast_k(
    const float* __restrict__ orow, float* __restrict__ out)
{
  int idx = blockIdx.x * 256 + threadIdx.x;           // float4 index
  const float4* o4 = (const float4*)orow;
  ((float4*)out)[idx] = o4[((idx >> 19) << 8) | (idx & 255)];
}

extern "C" void kernel_launch(void* const* d_in, const int* in_sizes, int n_in,
                              void* d_out, int out_size, void* d_ws, size_t ws_size,
                              hipStream_t stream) {
  (void)in_sizes; (void)n_in; (void)out_size;
  const float* xq = (const float*)d_in[0];
  const float* xk = (const float*)d_in[1];
  const float* xv = (const float*)d_in[2];
  const float* wq = (const float*)d_in[3];
  const float* bq = (const float*)d_in[4];
  const float* wk = (const float*)d_in[5];
  const float* bk = (const float*)d_in[6];
  const float* wv = (const float*)d_in[7];
  const float* bv = (const float*)d_in[8];
  const float* wo = (const float*)d_in[9];
  const float* bo = (const float*)d_in[10];
  float* out = (float*)d_out;

  // ---- small scratch (always in d_ws) ----
  char* base = (char*)d_ws;
  float* P = (float*)base;                     // B*H*S complex = 1 MB (fallback)
  size_t off = (size_t)SB * SH * SS * 2 * 4;
  int*   sidx = (int*)  (base + off); off += (size_t)SB * SH * KTOP * 4;
  float* sw   = (float*)(base + off); off += (size_t)SB * SH * KTOP * 4;
  float* xbar = (float*)(base + off); off += (size_t)SB * SH * SD * 4;
  float* att  = (float*)(base + off); off += (size_t)SB * SD * 4;
  float* orow = (float*)(base + off); off += (size_t)SB * SD * 4;

  // big-path layout in d_ws (ws poison fill shows 256 MiB available)
  size_t big0 = (off + 1048575) & ~(size_t)1048575;    // 1 MB align
  const size_t SZ_X = (size_t)SB * SS * SD * 2;        // 16 MB bf16 per split buf
  const size_t SZ_T = (size_t)SD * SB * SS * 4;        // 32 MB fp32 Qt/Kt
  const size_t SZ_W = (size_t)SD * 2048 * 2;           // 4 MB Wt
  const size_t SZ_P = (size_t)8 * 64 * 2048 * 8;       // 8 MB partial spectra
  const size_t SZ_XP = (size_t)KSL * 64 * 1024 * 4;    // 2 MB xbar partials
  size_t need_big = big0 + 4 * SZ_X + 2 * SZ_T + 2 * SZ_W + SZ_P + SZ_XP;

  if (ws_size >= need_big) {
    // ---------- big path: de-batched, no global atomics anywhere ----------
    char* bb = base + big0;
    short* Xqh = (short*)(bb);
    short* Xql = (short*)(bb + SZ_X);
    short* Xkh = (short*)(bb + 2 * SZ_X);
    short* Xkl = (short*)(bb + 3 * SZ_X);
    float* Qt  = (float*)(bb + 4 * SZ_X);
    float* Kt  = (float*)(bb + 4 * SZ_X + SZ_T);
    short* Wqt = (short*)(bb + 4 * SZ_X + 2 * SZ_T);
    short* Wkt = (short*)(bb + 4 * SZ_X + 2 * SZ_T + SZ_W);
    float2* Pp = (float2*)(bb + 4 * SZ_X + 2 * SZ_T + 2 * SZ_W);
    float* Xpart = (float*)(bb + 4 * SZ_X + 2 * SZ_T + 2 * SZ_W + SZ_P);

    splitwt_k<<<dim3(16, 16, 2), 256, 0, stream>>>(wq, wk, Wqt, Wkt);
    splitx2_k<<<dim3(SB * SS / 2, 2), 256, 0, stream>>>(xq, xk, Xqh, Xql, Xkh, Xkl);
    projm_k<<<dim3(8, SB * SS / 128, 2), 256, 0, stream>>>(
        Xqh, Xql, Wqt, bq, Qt, Xkh, Xkl, Wkt, bk, Kt, SB * SS);
    fftcorr_k<<<dim3(8, 16, SB), 256, 0, stream>>>(Qt, Kt, nullptr, Pp, SB * SS);
    ifft_topk_k<<<dim3(SB * SH), 256, 0, stream>>>(P, Pp, 8, sidx, sw);
    xbar_k<<<dim3(SB * SH, KSL), 256, 0, stream>>>(sidx, sw, xv, nullptr, Xpart);
    initbias_k<<<dim3(32), 256, 0, stream>>>(bv, bo, att, orow);
    attend_k<<<dim3(16, SB), 256, 0, stream>>>(nullptr, Xpart, KSL, wv, att);
  } else {
    // ---------- fallback: per-batch, atomic accumulate, scratch in d_out ----------
    char* ob = (char*)d_out;
    float* Qt  = (float*)(ob);                   // 8 MB [n][2048]
    float* Kt  = (float*)(ob + ( 8u << 20));     // 8 MB
    short* Wqt = (short*)(ob + (16u << 20));     // 4 MB
    short* Wkt = (short*)(ob + (20u << 20));     // 4 MB
    short* Xh  = (short*)(ob + (24u << 20));     // 4 MB per-batch split (hi)
    short* Xl  = (short*)(ob + (28u << 20));     // 4 MB (lo)

    hipMemsetAsync(P, 0, (size_t)SB * SH * SS * 2 * sizeof(float), stream);
    hipMemsetAsync(xbar, 0, (size_t)SB * SH * SD * sizeof(float), stream);
    splitwt_k<<<dim3(16, 16, 2), 256, 0, stream>>>(wq, wk, Wqt, Wkt);
    for (int b = 0; b < SB; ++b) {
      const float* xqb = xq + (size_t)b * SS * SD;
      const float* xkb = xk + (size_t)b * SS * SD;
      splitx2_k<<<dim3(SS / 2, 1), 256, 0, stream>>>(xqb, xqb, Xh, Xl, Xh, Xl);
      projm_k<<<dim3(8, SS / 128, 1), 256, 0, stream>>>(
          Xh, Xl, Wqt, bq, Qt, Xh, Xl, Wqt, bq, Qt, SS);
      splitx2_k<<<dim3(SS / 2, 1), 256, 0, stream>>>(xkb, xkb, Xh, Xl, Xh, Xl);
      projm_k<<<dim3(8, SS / 128, 1), 256, 0, stream>>>(
          Xh, Xl, Wkt, bk, Kt, Xh, Xl, Wkt, bk, Kt, SS);
      fftcorr_k<<<dim3(8, 16, 1), 256, 0, stream>>>(
          Qt, Kt, P + (size_t)b * SH * SS * 2, nullptr, SS);
    }
    ifft_topk_k<<<dim3(SB * SH), 256, 0, stream>>>(P, nullptr, 0, sidx, sw);
    xbar_k<<<dim3(SB * SH, KSL), 256, 0, stream>>>(sidx, sw, xv, xbar, nullptr);
    initbias_k<<<dim3(32), 256, 0, stream>>>(bv, bo, att, orow);
    attend_k<<<dim3(16, SB), 256, 0, stream>>>(xbar, nullptr, 0, wv, att);
  }

  oproj_k<<<dim3(16, SB), 256, 0, stream>>>(att, wo, orow);
  bcast_k<<<dim3(8192), 256, 0, stream>>>(orow, out);
}